// Round 11
// baseline (107.587 us; speedup 1.0000x reference)
//
#include <hip/hip_runtime.h>
#include <hip/hip_fp16.h>
#include <math.h>

// PhasorSample via type-2 NUFFT:
//   feat[n,c] = Re sum_{k in [-32,31], l in [0,63]} C[c,k,l]*w_l*e^{2pi i(k*u + l*v)}
// Steps:
//   1) phihat tables for the ES spread kernel (quadrature over [-2,2], J=4)
//   2+3) T[c,kk,Y] = sum_l Chat(l)*e^{2pi i l Y/Gy}   (deconv fused into y-DFT)
//   4) g[X,Y,c]  = Re sum_kk T * e^{2pi i k X/Gx}     -> packed to fp16
//   5) feat[n,c] = sum_{4x4 taps} g[Xi,Yj,c] * psi(px-Xi)*psi(py-Yj)
//      2 lanes per point (lane = 8 channels, one 16B fp16 load per tap).
// Grid 128x256x16 fp16 = 1 MB (L2-resident). J=4, beta=9.2 -> err ~1e-3 rel
// (abs ~1e-2 vs 0.25 tolerance). k_sample is L2-line-request-bound
// (~4us per M touches): touches = pts*taps = 4.2M.

#define NPTS  262144
#define GX    128
#define GY    256
#define BETA  9.2f
#define PI_F      3.14159265358979323846f
#define TWO_PI_F  6.28318530717958647692f

// ws layout (bytes):
//   0        : phit[128] floats  ([0..32] = phix, [64..127] = phiy)
//   1048576  : T[16*64*256] float2     (2 MB)
//   3145728  : gh[128*256*16] __half   (1 MB)

// ---- 1) spread-kernel Fourier transform, trapezoid quadrature over [-2,2] ---
__global__ void k_deconv(float* __restrict__ phit) {
    int b = blockIdx.x;                 // 0..32 -> x freq k=b ; 33..96 -> y freq l=b-33
    float xi; int idx;
    if (b < 33) { xi = (float)b * (1.0f / (float)GX); idx = b; }
    else        { xi = (float)(b - 33) * (1.0f / (float)GY); idx = 64 + (b - 33); }
    const int NQ = 1024;
    const float h = 4.0f / (float)NQ;
    float sum = 0.0f;
    for (int i = threadIdx.x; i <= NQ; i += blockDim.x) {
        float z  = -2.0f + h * (float)i;
        float t  = z * 0.5f;
        float s2 = fmaxf(1.0f - t * t, 0.0f);
        float psi = expf(BETA * (sqrtf(s2) - 1.0f));
        float w = (i == 0 || i == NQ) ? 0.5f : 1.0f;
        sum += w * psi * cosf(TWO_PI_F * xi * z);
    }
    __shared__ float red[256];
    red[threadIdx.x] = sum;
    __syncthreads();
    for (int s = 128; s > 0; s >>= 1) {
        if ((int)threadIdx.x < s) red[threadIdx.x] += red[threadIdx.x + s];
        __syncthreads();
    }
    if (threadIdx.x == 0) phit[idx] = red[0] * h;
}

// ---- 2+3) fused deconv + y-DFT: T[c,kk,Y] -----------------------------------
__global__ void k_ydft(const float* __restrict__ pr, const float* __restrict__ pim,
                       const float* __restrict__ gvar, const float* __restrict__ phit,
                       float2* __restrict__ T) {
    int ck = blockIdx.x;                 // c*64 + kk  (1024 blocks)
    int kk = ck & 63;
    int k  = (kk < 32) ? kk : kk - 64;
    int ak = (k < 0) ? -k : k;
    __shared__ float2 cs[64];
    if (threadIdx.x < 64) {
        int l = threadIdx.x;
        float fx = (float)k * (1.0f / 512.0f);
        float fy = (float)l * (1.0f / 512.0f);
        float var = gvar[0];
        float gauss = expf(-2.0f * PI_F * PI_F * var * (fx * fx + fy * fy));
        float w = (l == 0) ? 1.0f : 2.0f;
        // No Gx*Gy factor: Poisson gives e^{2pi i k u} ~ (1/phihat) * sum_X psi*e^{...}
        float scale = gauss * w / (phit[ak] * phit[64 + l]);
        int t = ck * 64 + l;
        cs[l] = make_float2(pr[t] * scale, pim[t] * scale);
    }
    __syncthreads();
    int Y = threadIdx.x;                 // 0..255
    float th = TWO_PI_F * (float)Y * (1.0f / (float)GY);
    float s1, c1;
    sincosf(th, &s1, &c1);
    float cr = 1.0f, sr = 0.0f, ar = 0.0f, ai = 0.0f;
    for (int l = 0; l < 64; ++l) {
        float2 cv = cs[l];
        ar = fmaf(cv.x, cr, ar); ar = fmaf(-cv.y, sr, ar);
        ai = fmaf(cv.x, sr, ai); ai = fmaf(cv.y, cr, ai);
        float cn = fmaf(cr, c1, -sr * s1);
        float sn = fmaf(sr, c1,  cr * s1);
        cr = cn; sr = sn;
    }
    T[ck * 256 + Y] = make_float2(ar, ai);
}

// ---- 4) x-DFT (real part) -> fp16 grid, 4 channels per thread ---------------
__global__ void k_xdft(const float2* __restrict__ T, __half* __restrict__ gh) {
    int X  = blockIdx.x;                 // 0..127
    int c0 = blockIdx.y * 4;             // channel group
    int Y  = threadIdx.x;                // 0..255
    float th = TWO_PI_F * (float)X * (1.0f / (float)GX);
    float s1, c1;
    sincosf(th, &s1, &c1);
    float sgn = (X & 1) ? -1.0f : 1.0f;  // e^{2pi i(kk-64)X/128} = w^kk * (-1)^X
    float cr = 1.0f, sr = 0.0f;
    float a0 = 0.f, a1 = 0.f, a2 = 0.f, a3 = 0.f;
    for (int kk = 0; kk < 64; ++kk) {
        float fr = (kk >= 32) ? cr * sgn : cr;
        float fi = (kk >= 32) ? sr * sgn : sr;
        float2 t0 = T[((c0 + 0) * 64 + kk) * 256 + Y];   // coalesced over Y
        float2 t1 = T[((c0 + 1) * 64 + kk) * 256 + Y];
        float2 t2 = T[((c0 + 2) * 64 + kk) * 256 + Y];
        float2 t3 = T[((c0 + 3) * 64 + kk) * 256 + Y];
        a0 = fmaf(t0.x, fr, a0); a0 = fmaf(-t0.y, fi, a0);
        a1 = fmaf(t1.x, fr, a1); a1 = fmaf(-t1.y, fi, a1);
        a2 = fmaf(t2.x, fr, a2); a2 = fmaf(-t2.y, fi, a2);
        a3 = fmaf(t3.x, fr, a3); a3 = fmaf(-t3.y, fi, a3);
        float cn = fmaf(cr, c1, -sr * s1);
        float sn = fmaf(sr, c1,  cr * s1);
        cr = cn; sr = sn;
    }
    union { __half2 h[2]; float2 f; } u;
    u.h[0] = __floats2half2_rn(a0, a1);
    u.h[1] = __floats2half2_rn(a2, a3);
    // byte offset of cell (X,Y), channel c0: X*8192 + Y*32 + c0*2
    *(float2*)((char*)gh + (size_t)X * 8192 + (size_t)Y * 32 + (size_t)c0 * 2) = u.f;
}

// ---- 5) per-point interpolation: 2 lanes/point, 4x4 taps, fp16 grid ---------
__global__ __launch_bounds__(256) void k_sample(const float2* __restrict__ coord,
                                                const __half* __restrict__ gh,
                                                float* __restrict__ out) {
    int n   = blockIdx.x * 128 + (threadIdx.x >> 1);  // 128 points per block
    int sub = threadIdx.x & 1;                        // channels 8*sub .. 8*sub+7
    float2 uv = coord[n];                             // broadcast across 2 lanes
    float px = uv.x * (float)GX;
    float py = uv.y * (float)GY;
    int ix0 = (int)floorf(px) - 1;                    // J=4: z in (-2, 2)
    int iy0 = (int)floorf(py) - 1;
    float wx[4], wy[4];
#pragma unroll
    for (int i = 0; i < 4; ++i) {                     // replicated x2 lanes
        float zx = px - (float)(ix0 + i);
        float tx = zx * 0.5f;
        float sx2 = fmaxf(1.0f - tx * tx, 0.0f);
        wx[i] = __expf(BETA * (sqrtf(sx2) - 1.0f));
        float zy = py - (float)(iy0 + i);
        float ty = zy * 0.5f;
        float sy2 = fmaxf(1.0f - ty * ty, 0.0f);
        wy[i] = __expf(BETA * (sqrtf(sy2) - 1.0f));
    }
    int yo[4];
#pragma unroll
    for (int j = 0; j < 4; ++j)
        yo[j] = ((iy0 + j) & (GY - 1)) * 32 + sub * 16;   // byte offsets
    float a0 = 0.f, a1 = 0.f, a2 = 0.f, a3 = 0.f;
    float a4 = 0.f, a5 = 0.f, a6 = 0.f, a7 = 0.f;
#pragma unroll
    for (int i = 0; i < 4; ++i) {
        const char* rowp = (const char*)gh + (size_t)(((ix0 + i) & (GX - 1)) * 8192);
        float wxi = wx[i];
#pragma unroll
        for (int j = 0; j < 4; ++j) {
            float4 raw = *(const float4*)(rowp + yo[j]);     // one 16B load = 8 fp16 ch
            __half2 h01 = *reinterpret_cast<const __half2*>(&raw.x);
            __half2 h23 = *reinterpret_cast<const __half2*>(&raw.y);
            __half2 h45 = *reinterpret_cast<const __half2*>(&raw.z);
            __half2 h67 = *reinterpret_cast<const __half2*>(&raw.w);
            float2 v01 = __half22float2(h01);
            float2 v23 = __half22float2(h23);
            float2 v45 = __half22float2(h45);
            float2 v67 = __half22float2(h67);
            float w = wxi * wy[j];
            a0 = fmaf(w, v01.x, a0);
            a1 = fmaf(w, v01.y, a1);
            a2 = fmaf(w, v23.x, a2);
            a3 = fmaf(w, v23.y, a3);
            a4 = fmaf(w, v45.x, a4);
            a5 = fmaf(w, v45.y, a5);
            a6 = fmaf(w, v67.x, a6);
            a7 = fmaf(w, v67.y, a7);
        }
    }
    float* o = out + (size_t)n * 16 + sub * 8;
    *(float4*)(o + 0) = make_float4(a0, a1, a2, a3);
    *(float4*)(o + 4) = make_float4(a4, a5, a6, a7);
}

extern "C" void kernel_launch(void* const* d_in, const int* in_sizes, int n_in,
                              void* d_out, int out_size, void* d_ws, size_t ws_size,
                              hipStream_t stream) {
    const float* coord = (const float*)d_in[0];   // [N,2]
    const float* preal = (const float*)d_in[1];   // [1,16,64,64]
    const float* pimag = (const float*)d_in[2];
    const float* gvar  = (const float*)d_in[3];   // scalar

    char*   ws   = (char*)d_ws;
    float*  phit = (float*)(ws + 0);
    float2* T    = (float2*)(ws + 1048576);
    __half* gh   = (__half*)(ws + 3145728);
    float*  out  = (float*)d_out;

    hipLaunchKernelGGL(k_deconv, dim3(97),          dim3(256), 0, stream, phit);
    hipLaunchKernelGGL(k_ydft,   dim3(1024),        dim3(256), 0, stream, preal, pimag, gvar, phit, T);
    hipLaunchKernelGGL(k_xdft,   dim3(128, 4),      dim3(256), 0, stream, T, gh);
    hipLaunchKernelGGL(k_sample, dim3(NPTS/128),    dim3(256), 0, stream, (const float2*)coord, gh, out);
}

// Round 13
// 102.314 us; speedup vs baseline: 1.0515x; 1.0515x over previous
//
#include <hip/hip_runtime.h>
#include <hip/hip_fp16.h>
#include <math.h>

// PhasorSample via type-2 NUFFT:
//   feat[n,c] = Re sum_{k in [-32,31], l in [0,63]} C[c,k,l]*w_l*e^{2pi i(k*u + l*v)}
// Steps:
//   1) phihat tables for the ES spread kernel (quadrature over [-2,2], J=4)
//   2+3) T[c,kk,Y] = sum_l Chat(l)*e^{2pi i l Y/Gy}   (deconv fused into y-DFT)
//   4) g[X,Y,c]  = Re sum_kk T * e^{2pi i k X/Gx}     -> packed to fp16
//   5) feat[n,c] = sum_{4x4 taps} g[Xi,Yj,c] * psi(px-Xi)*psi(py-Yj)
//      2 lanes per point (lane = 8 channels); tap inner loop is PACKED fp16:
//      4x v_pk_fma_f16 per tap (VALU ~7/tap vs 17 for unpack-to-fp32).
// Grid 128x256x16 fp16 = 1 MB (L2-resident). J=4, beta=9.2 -> err ~1e-3 rel;
// fp16 accumulate adds ~0.05 abs worst-case vs 0.25 tolerance (passed J=8/6/5/4).
// k_sample model: ~4us per M line-touches (touches = pts*taps = 4.2M) + VALU.

#define NPTS  262144
#define GX    128
#define GY    256
#define BETA  9.2f
#define PI_F      3.14159265358979323846f
#define TWO_PI_F  6.28318530717958647692f

// ws layout (bytes):
//   0        : phit[128] floats  ([0..32] = phix, [64..127] = phiy)
//   1048576  : T[16*64*256] float2     (2 MB)
//   3145728  : gh[128*256*16] __half   (1 MB)

// ---- 1) spread-kernel Fourier transform, trapezoid quadrature over [-2,2] ---
__global__ void k_deconv(float* __restrict__ phit) {
    int b = blockIdx.x;                 // 0..32 -> x freq k=b ; 33..96 -> y freq l=b-33
    float xi; int idx;
    if (b < 33) { xi = (float)b * (1.0f / (float)GX); idx = b; }
    else        { xi = (float)(b - 33) * (1.0f / (float)GY); idx = 64 + (b - 33); }
    const int NQ = 256;
    const float h = 4.0f / (float)NQ;
    float sum = 0.0f;
    for (int i = threadIdx.x; i <= NQ; i += blockDim.x) {
        float z  = -2.0f + h * (float)i;
        float t  = z * 0.5f;
        float s2 = fmaxf(1.0f - t * t, 0.0f);
        float psi = expf(BETA * (sqrtf(s2) - 1.0f));
        float w = (i == 0 || i == NQ) ? 0.5f : 1.0f;
        sum += w * psi * cosf(TWO_PI_F * xi * z);
    }
    __shared__ float red[256];
    red[threadIdx.x] = sum;
    __syncthreads();
    for (int s = 128; s > 0; s >>= 1) {
        if ((int)threadIdx.x < s) red[threadIdx.x] += red[threadIdx.x + s];
        __syncthreads();
    }
    if (threadIdx.x == 0) phit[idx] = red[0] * h;
}

// ---- 2+3) fused deconv + y-DFT: T[c,kk,Y] -----------------------------------
__global__ void k_ydft(const float* __restrict__ pr, const float* __restrict__ pim,
                       const float* __restrict__ gvar, const float* __restrict__ phit,
                       float2* __restrict__ T) {
    int ck = blockIdx.x;                 // c*64 + kk  (1024 blocks)
    int kk = ck & 63;
    int k  = (kk < 32) ? kk : kk - 64;
    int ak = (k < 0) ? -k : k;
    __shared__ float2 cs[64];
    if (threadIdx.x < 64) {
        int l = threadIdx.x;
        float fx = (float)k * (1.0f / 512.0f);
        float fy = (float)l * (1.0f / 512.0f);
        float var = gvar[0];
        float gauss = expf(-2.0f * PI_F * PI_F * var * (fx * fx + fy * fy));
        float w = (l == 0) ? 1.0f : 2.0f;
        // No Gx*Gy factor: Poisson gives e^{2pi i k u} ~ (1/phihat) * sum_X psi*e^{...}
        float scale = gauss * w / (phit[ak] * phit[64 + l]);
        int t = ck * 64 + l;
        cs[l] = make_float2(pr[t] * scale, pim[t] * scale);
    }
    __syncthreads();
    int Y = threadIdx.x;                 // 0..255
    float th = TWO_PI_F * (float)Y * (1.0f / (float)GY);
    float s1, c1;
    sincosf(th, &s1, &c1);
    float cr = 1.0f, sr = 0.0f, ar = 0.0f, ai = 0.0f;
    for (int l = 0; l < 64; ++l) {
        float2 cv = cs[l];
        ar = fmaf(cv.x, cr, ar); ar = fmaf(-cv.y, sr, ar);
        ai = fmaf(cv.x, sr, ai); ai = fmaf(cv.y, cr, ai);
        float cn = fmaf(cr, c1, -sr * s1);
        float sn = fmaf(sr, c1,  cr * s1);
        cr = cn; sr = sn;
    }
    T[ck * 256 + Y] = make_float2(ar, ai);
}

// ---- 4) x-DFT (real part) -> fp16 grid, 4 channels per thread ---------------
__global__ void k_xdft(const float2* __restrict__ T, __half* __restrict__ gh) {
    int X  = blockIdx.x;                 // 0..127
    int c0 = blockIdx.y * 4;             // channel group
    int Y  = threadIdx.x;                // 0..255
    float th = TWO_PI_F * (float)X * (1.0f / (float)GX);
    float s1, c1;
    sincosf(th, &s1, &c1);
    float sgn = (X & 1) ? -1.0f : 1.0f;  // e^{2pi i(kk-64)X/128} = w^kk * (-1)^X
    float cr = 1.0f, sr = 0.0f;
    float a0 = 0.f, a1 = 0.f, a2 = 0.f, a3 = 0.f;
    for (int kk = 0; kk < 64; ++kk) {
        float fr = (kk >= 32) ? cr * sgn : cr;
        float fi = (kk >= 32) ? sr * sgn : sr;
        float2 t0 = T[((c0 + 0) * 64 + kk) * 256 + Y];   // coalesced over Y
        float2 t1 = T[((c0 + 1) * 64 + kk) * 256 + Y];
        float2 t2 = T[((c0 + 2) * 64 + kk) * 256 + Y];
        float2 t3 = T[((c0 + 3) * 64 + kk) * 256 + Y];
        a0 = fmaf(t0.x, fr, a0); a0 = fmaf(-t0.y, fi, a0);
        a1 = fmaf(t1.x, fr, a1); a1 = fmaf(-t1.y, fi, a1);
        a2 = fmaf(t2.x, fr, a2); a2 = fmaf(-t2.y, fi, a2);
        a3 = fmaf(t3.x, fr, a3); a3 = fmaf(-t3.y, fi, a3);
        float cn = fmaf(cr, c1, -sr * s1);
        float sn = fmaf(sr, c1,  cr * s1);
        cr = cn; sr = sn;
    }
    union { __half2 h[2]; float2 f; } u;
    u.h[0] = __floats2half2_rn(a0, a1);
    u.h[1] = __floats2half2_rn(a2, a3);
    // byte offset of cell (X,Y), channel c0: X*8192 + Y*32 + c0*2
    *(float2*)((char*)gh + (size_t)X * 8192 + (size_t)Y * 32 + (size_t)c0 * 2) = u.f;
}

// ---- 5) per-point interpolation: 2 lanes/point, 4x4 taps, packed fp16 fma ---
__global__ __launch_bounds__(256) void k_sample(const float2* __restrict__ coord,
                                                const __half* __restrict__ gh,
                                                float* __restrict__ out) {
    int n   = blockIdx.x * 128 + (threadIdx.x >> 1);  // 128 points per block
    int sub = threadIdx.x & 1;                        // channels 8*sub .. 8*sub+7
    float2 uv = coord[n];                             // broadcast across 2 lanes
    float px = uv.x * (float)GX;
    float py = uv.y * (float)GY;
    int ix0 = (int)floorf(px) - 1;                    // J=4: z in (-2, 2)
    int iy0 = (int)floorf(py) - 1;
    float wx[4], wy[4];
#pragma unroll
    for (int i = 0; i < 4; ++i) {                     // replicated x2 lanes
        float zx = px - (float)(ix0 + i);
        float tx = zx * 0.5f;
        float sx2 = fmaxf(1.0f - tx * tx, 0.0f);
        wx[i] = __expf(BETA * (sqrtf(sx2) - 1.0f));
        float zy = py - (float)(iy0 + i);
        float ty = zy * 0.5f;
        float sy2 = fmaxf(1.0f - ty * ty, 0.0f);
        wy[i] = __expf(BETA * (sqrtf(sy2) - 1.0f));
    }
    int yo[4];
#pragma unroll
    for (int j = 0; j < 4; ++j)
        yo[j] = ((iy0 + j) & (GY - 1)) * 32 + sub * 16;   // byte offsets
    __half2 acc01 = __float2half2_rn(0.f);
    __half2 acc23 = __float2half2_rn(0.f);
    __half2 acc45 = __float2half2_rn(0.f);
    __half2 acc67 = __float2half2_rn(0.f);
#pragma unroll
    for (int i = 0; i < 4; ++i) {
        const char* rowp = (const char*)gh + (size_t)(((ix0 + i) & (GX - 1)) * 8192);
        float wxi = wx[i];
#pragma unroll
        for (int j = 0; j < 4; ++j) {
            float4 raw = *(const float4*)(rowp + yo[j]);     // one 16B load = 8 fp16 ch
            const __half2* hp = reinterpret_cast<const __half2*>(&raw);
            __half2 w2 = __float2half2_rn(wxi * wy[j]);
            acc01 = __hfma2(w2, hp[0], acc01);
            acc23 = __hfma2(w2, hp[1], acc23);
            acc45 = __hfma2(w2, hp[2], acc45);
            acc67 = __hfma2(w2, hp[3], acc67);
        }
    }
    float2 f01 = __half22float2(acc01);
    float2 f23 = __half22float2(acc23);
    float2 f45 = __half22float2(acc45);
    float2 f67 = __half22float2(acc67);
    float* o = out + (size_t)n * 16 + sub * 8;
    *(float4*)(o + 0) = make_float4(f01.x, f01.y, f23.x, f23.y);
    *(float4*)(o + 4) = make_float4(f45.x, f45.y, f67.x, f67.y);
}

extern "C" void kernel_launch(void* const* d_in, const int* in_sizes, int n_in,
                              void* d_out, int out_size, void* d_ws, size_t ws_size,
                              hipStream_t stream) {
    const float* coord = (const float*)d_in[0];   // [N,2]
    const float* preal = (const float*)d_in[1];   // [1,16,64,64]
    const float* pimag = (const float*)d_in[2];
    const float* gvar  = (const float*)d_in[3];   // scalar

    char*   ws   = (char*)d_ws;
    float*  phit = (float*)(ws + 0);
    float2* T    = (float2*)(ws + 1048576);
    __half* gh   = (__half*)(ws + 3145728);
    float*  out  = (float*)d_out;

    hipLaunchKernelGGL(k_deconv, dim3(97),          dim3(256), 0, stream, phit);
    hipLaunchKernelGGL(k_ydft,   dim3(1024),        dim3(256), 0, stream, preal, pimag, gvar, phit, T);
    hipLaunchKernelGGL(k_xdft,   dim3(128, 4),      dim3(256), 0, stream, T, gh);
    hipLaunchKernelGGL(k_sample, dim3(NPTS/128),    dim3(256), 0, stream, (const float2*)coord, gh, out);
}